// Round 5
// baseline (181.393 us; speedup 1.0000x reference)
//
#include <hip/hip_runtime.h>
#include <hip/hip_bf16.h>
#include <math.h>

#define NUM_CLASSES 10
#define BATCH 2048
#define DIM 128
#define INV_T 14.285714285714286f   // 1/0.07; TEMPERATURE/BASE_TEMPERATURE = 1
#define NTILE 16                    // 2048/128 row stripes
#define NPAIR 136                   // upper-triangular 128x128 block pairs

typedef __attribute__((ext_vector_type(8))) short bf16x8;   // 8 bf16 = 4 VGPRs
typedef __attribute__((ext_vector_type(4))) float f32x4;    // MFMA accumulator

// ---------------------------------------------------------------------------
// 1) Row-normalize preds -> bf16 g; fuse zeroing of denom/s2 accumulators.
// ---------------------------------------------------------------------------
__global__ __launch_bounds__(256) void normalize_kernel(
    const float* __restrict__ preds, __hip_bfloat16* __restrict__ g,
    float* __restrict__ zero_buf)
{
    int b = blockIdx.x;
    int t = threadIdx.x;
    if (t < 8) zero_buf[b * 8 + t] = 0.0f;   // 5120 blocks * 8 = 40960 floats

    int row  = b * 4 + (t >> 6);
    int lane = t & 63;
    const float2* src = (const float2*)(preds + (size_t)row * DIM);
    float2 v = src[lane];
    float ss = v.x * v.x + v.y * v.y;
#pragma unroll
    for (int m = 32; m; m >>= 1) ss += __shfl_xor(ss, m, 64);
    float rn = 1.0f / sqrtf(ss);
    __hip_bfloat162 o;
    o.x = __float2bfloat16(v.x * rn);
    o.y = __float2bfloat16(v.y * rn);
    *(__hip_bfloat162*)(g + (size_t)row * DIM + lane * 2) = o;
}

// ---------------------------------------------------------------------------
// 2) MFMA Gram, upper-tri blocks only, NO LDS staging: operands are
//    L2-resident (512 KB/class), so each wave loads its MFMA fragments
//    directly from global (16 rows x 64B per wave-instr, coalesced).
//    A-frag layout == row-major 16B chunks at (row)*128 + quad*8.
//    Epilogue: per-row/col partials via LDS float atomics (2 KB).
// ---------------------------------------------------------------------------
__global__ __launch_bounds__(256) void gram_kernel(
    const __hip_bfloat16* __restrict__ g, const int* __restrict__ target,
    float* __restrict__ denom, float* __restrict__ s2)
{
    // decode upper-tri pair (by <= bx)
    int p = blockIdx.x;
    int by = 0, rem = NTILE;
    while (p >= rem) { p -= rem; --rem; ++by; }
    const int bx   = by + p;
    const int cls  = blockIdx.y;
    const int row0 = by * 128;
    const int col0 = bx * 128;
    const bool isDiag = (by == bx);
    const ushort* gc = (const ushort*)g + (size_t)cls * BATCH * DIM;

    const int t    = threadIdx.x;
    const int wid  = t >> 6;
    const int lane = t & 63;
    const int tx   = lane & 15;         // frag row sel; C/D: col = lane&15
    const int quad = lane >> 4;         // frag k-chunk;  C/D: row = quad*4+reg
    const int wm   = (wid >> 1) * 64;
    const int wn   = (wid & 1) * 64;

    // fragment base pointers: row-major, 16B chunk at quad*8 elems
    const ushort* aBase = gc + (size_t)(row0 + wm + tx) * DIM + quad * 8;
    const ushort* bBase = gc + (size_t)(col0 + wn + tx) * DIM + quad * 8;

    f32x4 acc[4][4] = {};
#pragma unroll
    for (int ks = 0; ks < 4; ++ks) {
        bf16x8 af[4], bg[4];
#pragma unroll
        for (int i = 0; i < 4; ++i)
            af[i] = *(const bf16x8*)(aBase + i * 16 * DIM + ks * 32);
#pragma unroll
        for (int j = 0; j < 4; ++j)
            bg[j] = *(const bf16x8*)(bBase + j * 16 * DIM + ks * 32);
#pragma unroll
        for (int i = 0; i < 4; ++i)
#pragma unroll
            for (int j = 0; j < 4; ++j)
                acc[i][j] = __builtin_amdgcn_mfma_f32_16x16x32_bf16(
                    af[i], bg[j], acc[i][j], 0, 0, 0);
    }

    // ---- epilogue: LDS float-atomic accumulation (2 KB) ----
    __shared__ float rowDen[128], rowSp[128], colDen[128], colSp[128];
    if (t < 128) { rowDen[t] = 0.0f; rowSp[t] = 0.0f; }
    else         { colDen[t - 128] = 0.0f; colSp[t - 128] = 0.0f; }

    unsigned laMask = 0;
#pragma unroll
    for (int i = 0; i < 4; ++i)
#pragma unroll
        for (int r = 0; r < 4; ++r)
            if (target[row0 + wm + i * 16 + quad * 4 + r] == cls)
                laMask |= 1u << (i * 4 + r);
    int lb[4];
#pragma unroll
    for (int j = 0; j < 4; ++j) lb[j] = (target[col0 + wn + j * 16 + tx] == cls);
    __syncthreads();

    float cden[4] = {}, csp[4] = {};
#pragma unroll
    for (int i = 0; i < 4; ++i) {
#pragma unroll
        for (int r = 0; r < 4; ++r) {
            int rloc = wm + i * 16 + quad * 4 + r;
            int rg = row0 + rloc;
            unsigned la = (laMask >> (i * 4 + r)) & 1;
            float den = 0.0f, sp = 0.0f;
#pragma unroll
            for (int j = 0; j < 4; ++j) {
                int cg = col0 + wn + j * 16 + tx;
                float logit = acc[i][j][r] * INV_T;
                float e = __expf(logit);
                bool dg = isDiag && (cg == rg);
                e = dg ? 0.0f : e;
                bool same = (la == (unsigned)lb[j]) && !dg;
                float sl = same ? logit : 0.0f;
                den += e; sp += sl;
                cden[j] += e; csp[j] += sl;
            }
            atomicAdd(&rowDen[rloc], den);
            atomicAdd(&rowSp[rloc], sp);
        }
    }
    if (!isDiag) {
#pragma unroll
        for (int j = 0; j < 4; ++j) {
            int cloc = wn + j * 16 + tx;
            atomicAdd(&colDen[cloc], cden[j]);
            atomicAdd(&colSp[cloc], csp[j]);
        }
    }
    __syncthreads();

    if (t < 128) {
        atomicAdd(&denom[cls * BATCH + row0 + t], rowDen[t]);
        atomicAdd(&s2   [cls * BATCH + row0 + t], rowSp[t]);
    } else if (!isDiag) {
        int u = t - 128;
        atomicAdd(&denom[cls * BATCH + col0 + u], colDen[u]);
        atomicAdd(&s2   [cls * BATCH + col0 + u], colSp[u]);
    }
}

// ---------------------------------------------------------------------------
// 3) Finalize (single block, 1024 threads).
// ---------------------------------------------------------------------------
__global__ __launch_bounds__(1024) void final_kernel(
    const float* __restrict__ denom, const float* __restrict__ s2,
    const int* __restrict__ target, const float* __restrict__ log_vars,
    float* __restrict__ out)
{
    __shared__ int counts[NUM_CLASSES];
    __shared__ float wsum[16];
    int t = threadIdx.x;
    if (t < NUM_CLASSES) counts[t] = 0;
    __syncthreads();
    for (int i = t; i < BATCH; i += 1024) atomicAdd(&counts[target[i]], 1);
    __syncthreads();

    float partial = 0.0f;
    for (int idx = t; idx < NUM_CLASSES * BATCH; idx += 1024) {
        int i = idx >> 11;
        int a = idx & (BATCH - 1);
        int cnt = (target[a] == i) ? (counts[i] - 1) : (BATCH - counts[i] - 1);
        float mlpp = s2[idx] / (float)cnt - logf(denom[idx]);
        partial += __expf(-log_vars[i]) * mlpp;
    }
#pragma unroll
    for (int m = 32; m; m >>= 1) partial += __shfl_xor(partial, m, 64);
    if ((t & 63) == 0) wsum[t >> 6] = partial;
    __syncthreads();
    if (t == 0) {
        float tot = 0.0f;
        for (int w = 0; w < 16; ++w) tot += wsum[w];
        float lvsum = 0.0f;
        for (int i = 0; i < NUM_CLASSES; ++i) lvsum += log_vars[i];
        out[0] = -tot / (float)BATCH + lvsum;
    }
}

// ---------------------------------------------------------------------------
extern "C" void kernel_launch(void* const* d_in, const int* in_sizes, int n_in,
                              void* d_out, int out_size, void* d_ws, size_t ws_size,
                              hipStream_t stream)
{
    const float* preds    = (const float*)d_in[0];   // [10,2048,128] f32
    const int*   target   = (const int*)  d_in[1];   // [2048]
    const float* log_vars = (const float*)d_in[2];   // [10]
    float* out = (float*)d_out;

    __hip_bfloat16* gbf = (__hip_bfloat16*)d_ws;              // 10*2048*128 bf16
    float* denom = (float*)((char*)d_ws + (size_t)NUM_CLASSES * BATCH * DIM * 2);
    float* s2    = denom + (size_t)NUM_CLASSES * BATCH;

    normalize_kernel<<<NUM_CLASSES * BATCH / 4, 256, 0, stream>>>(preds, gbf, denom);
    gram_kernel<<<dim3(NPAIR, NUM_CLASSES), 256, 0, stream>>>(gbf, target, denom, s2);
    final_kernel<<<1, 1024, 0, stream>>>(denom, s2, target, log_vars, out);
}

// Round 6
// 102.692 us; speedup vs baseline: 1.7664x; 1.7664x over previous
//
#include <hip/hip_runtime.h>
#include <hip/hip_bf16.h>
#include <math.h>

#define NUM_CLASSES 10
#define BATCH 2048
#define DIM 128
#define INV_T 14.285714285714286f   // 1/0.07; TEMPERATURE/BASE_TEMPERATURE = 1
#define NTILE 16                    // 2048/128 row stripes
#define NPAIR 136                   // upper-triangular 128x128 block pairs

typedef __attribute__((ext_vector_type(8))) short bf16x8;   // 8 bf16 = 4 VGPRs
typedef __attribute__((ext_vector_type(4))) float f32x4;    // MFMA accumulator

// Async 16B-per-lane global->LDS. LDS dest = wave-uniform base + lane*16.
__device__ __forceinline__ void load_lds16(const void* g, void* lds) {
    __builtin_amdgcn_global_load_lds(
        (const __attribute__((address_space(1))) unsigned int*)g,
        (__attribute__((address_space(3))) unsigned int*)lds,
        16, 0, 0);
}

// ---------------------------------------------------------------------------
// 1) Row-normalize preds -> bf16 g; fuse zeroing of denom accumulators.
// ---------------------------------------------------------------------------
__global__ __launch_bounds__(256) void normalize_kernel(
    const float* __restrict__ preds, __hip_bfloat16* __restrict__ g,
    float* __restrict__ zero_buf)
{
    int b = blockIdx.x;
    int t = threadIdx.x;
    if (t < 8) zero_buf[b * 8 + t] = 0.0f;   // 5120*8 = 40960 floats (covers denom)

    int row  = b * 4 + (t >> 6);
    int lane = t & 63;
    const float2* src = (const float2*)(preds + (size_t)row * DIM);
    float2 v = src[lane];
    float ss = v.x * v.x + v.y * v.y;
#pragma unroll
    for (int m = 32; m; m >>= 1) ss += __shfl_xor(ss, m, 64);
    float rn = 1.0f / sqrtf(ss);
    __hip_bfloat162 o;
    o.x = __float2bfloat16(v.x * rn);
    o.y = __float2bfloat16(v.y * rn);
    *(__hip_bfloat162*)(g + (size_t)row * DIM + lane * 2) = o;
}

// ---------------------------------------------------------------------------
// 1b) Per-class group sums G[cls][la][d] = sum of ghat rows with/without
//     label==cls; class counts; and out init = sum(log_vars).
//     10 blocks x 1024 threads: t = (slice 0..7) * 128 + d.
// ---------------------------------------------------------------------------
__global__ __launch_bounds__(1024) void gsum_kernel(
    const __hip_bfloat16* __restrict__ g, const int* __restrict__ target,
    const float* __restrict__ log_vars, float* __restrict__ Gsum,
    int* __restrict__ counts, float* __restrict__ out)
{
    const int cls = blockIdx.x;
    const int t = threadIdx.x;
    const int d = t & 127, sl = t >> 7;
    const __hip_bfloat16* gc = g + (size_t)cls * BATCH * DIM;

    float a0 = 0.0f, a1 = 0.0f;
    int c1 = 0;
    for (int r8 = 0; r8 < 256; ++r8) {
        int row = sl * 256 + r8;                 // wave-uniform
        int lbl = target[row];
        float v = __bfloat162float(gc[(size_t)row * DIM + d]);
        if (lbl == cls) { a1 += v; ++c1; } else { a0 += v; }
    }
    __shared__ float red[2][8][128];
    __shared__ int cpart[8];
    red[0][sl][d] = a0;
    red[1][sl][d] = a1;
    if (d == 0) cpart[sl] = c1;
    __syncthreads();
    if (t < 256) {
        int h = t >> 7, dd = t & 127;
        float s = 0.0f;
#pragma unroll
        for (int k = 0; k < 8; ++k) s += red[h][k][dd];
        Gsum[cls * 256 + h * 128 + dd] = s;
    }
    if (t == 0) {
        int c = 0;
#pragma unroll
        for (int k = 0; k < 8; ++k) c += cpart[k];
        counts[cls] = c;
        if (cls == 0) {
            float lv = 0.0f;
            for (int i = 0; i < NUM_CLASSES; ++i) lv += log_vars[i];
            out[0] = lv;
        }
    }
}

// ---------------------------------------------------------------------------
// 2) MFMA Gram, upper-tri blocks only, async global_load_lds staging with
//    XOR-swizzled layout (round-4 verified). Epilogue now den-only:
//    e = exp(logit), accumulate per-row and per-col sums, LDS transpose,
//    one global atomic per row.
// ---------------------------------------------------------------------------
__global__ __launch_bounds__(256) void gram_kernel(
    const __hip_bfloat16* __restrict__ g, float* __restrict__ denom)
{
    // decode upper-tri pair (by <= bx)
    int p = blockIdx.x;
    int by = 0, rem = NTILE;
    while (p >= rem) { p -= rem; --rem; ++by; }
    const int bx   = by + p;
    const int cls  = blockIdx.y;
    const int row0 = by * 128;
    const int col0 = bx * 128;
    const bool isDiag = (by == bx);
    const ushort* gc = (const ushort*)g + (size_t)cls * BATCH * DIM;

    __shared__ __align__(16) ushort smem[2 * 128 * 128];   // 64 KiB
    ushort* As = smem;
    ushort* Bs = smem + 128 * 128;

    const int t    = threadIdx.x;
    const int wid  = t >> 6;
    const int lane = t & 63;
    const int tx   = lane & 15;         // frag row sel; C/D: col = lane&15
    const int quad = lane >> 4;         // frag k-chunk;  C/D: row = quad*4+reg
    const int wm   = (wid >> 1) * 64;
    const int wn   = (wid & 1) * 64;

    // ---- async staging ----
    const int lr = lane >> 4;
    const int lp = lane & 15;
#pragma unroll
    for (int s = 0; s < 8; ++s) {
        int rb = s * 16 + wid * 4;      // wave-uniform row base
        int r  = rb + lr;
        int c  = lp ^ (r & 15);         // fetch chunk c into position lp
        load_lds16(gc + (size_t)(row0 + r) * DIM + c * 8, &As[rb * 128]);
        if (!isDiag)
            load_lds16(gc + (size_t)(col0 + r) * DIM + c * 8, &Bs[rb * 128]);
    }
    __syncthreads();

    // ---- MFMA main loop: K=128 in 4 slices of 32 ----
    const ushort* BsR = isDiag ? As : Bs;
    f32x4 acc[4][4] = {};
#pragma unroll
    for (int ks = 0; ks < 4; ++ks) {
        bf16x8 af[4], bg[4];
#pragma unroll
        for (int i = 0; i < 4; ++i) {
            int pa = ((ks * 4 + quad) ^ tx) * 8;   // swizzled chunk offset
            af[i] = *(const bf16x8*)&As [(wm + i * 16 + tx) * 128 + pa];
            bg[i] = *(const bf16x8*)&BsR[(wn + i * 16 + tx) * 128 + pa];
        }
#pragma unroll
        for (int i = 0; i < 4; ++i)
#pragma unroll
            for (int j = 0; j < 4; ++j)
                acc[i][j] = __builtin_amdgcn_mfma_f32_16x16x32_bf16(
                    af[i], bg[j], acc[i][j], 0, 0, 0);
    }
    __syncthreads();   // tile reads done; safe to reuse LDS

    // ---- epilogue: exp row/col partial sums -> LDS transpose -> atomics ----
    float* rbuf = (float*)smem;                 // [wid][64 x17] floats, 17408 B
    float* cbuf = (float*)smem + 4 * 1088;      // [wid][64 x5]  floats,  5120 B
    float cden[4] = {};

#pragma unroll
    for (int i = 0; i < 4; ++i) {
#pragma unroll
        for (int r = 0; r < 4; ++r) {
            float den = 0.0f;
            if (isDiag) {
                int rg = row0 + wm + i * 16 + quad * 4 + r;
#pragma unroll
                for (int j = 0; j < 4; ++j) {
                    int cg = col0 + wn + j * 16 + tx;
                    float e = __expf(acc[i][j][r] * INV_T);
                    e = (cg == rg) ? 0.0f : e;
                    den += e; cden[j] += e;
                }
            } else {
#pragma unroll
                for (int j = 0; j < 4; ++j) {
                    float e = __expf(acc[i][j][r] * INV_T);
                    den += e; cden[j] += e;
                }
            }
            rbuf[wid * 1088 + (i * 16 + quad * 4 + r) * 17 + tx] = den;
        }
    }
#pragma unroll
    for (int j = 0; j < 4; ++j)
        cbuf[wid * 320 + (j * 16 + tx) * 5 + quad] = cden[j];
    __syncthreads();

    if (t < 128) {
        int rl = t & 63, grp = t >> 6;          // wids 2*grp, 2*grp+1
        float den = 0.0f;
#pragma unroll
        for (int w = 0; w < 2; ++w) {
            int base = (2 * grp + w) * 1088 + rl * 17;
#pragma unroll
            for (int x = 0; x < 16; ++x) den += rbuf[base + x];
        }
        atomicAdd(&denom[cls * BATCH + row0 + t], den);
    } else if (!isDiag) {
        int u = t - 128, cl = u & 63, grp = u >> 6;   // wids grp, grp+2
        float den = 0.0f;
#pragma unroll
        for (int w = 0; w < 2; ++w) {
            int base = (grp + 2 * w) * 320 + cl * 5;
#pragma unroll
            for (int q = 0; q < 4; ++q) den += cbuf[base + q];
        }
        atomicAdd(&denom[cls * BATCH + col0 + u], den);
    }
}

// ---------------------------------------------------------------------------
// 3) Finalize, parallel: one thread per (cls,row). s2 via group-sum dot:
//    s2 = INV_T*(ghat_a . G[cls][la] - 1).  80 blocks x 256 threads.
// ---------------------------------------------------------------------------
__global__ __launch_bounds__(256) void final_kernel(
    const __hip_bfloat16* __restrict__ g, const float* __restrict__ denom,
    const int* __restrict__ target, const float* __restrict__ log_vars,
    const float* __restrict__ Gsum, const int* __restrict__ counts,
    float* __restrict__ out)
{
    __shared__ float gs[256];
    __shared__ float wred[4];
    const int t   = threadIdx.x;
    const int idx = blockIdx.x * 256 + t;
    const int cls = idx >> 11;            // block-uniform (2048 % 256 == 0)
    const int a   = idx & (BATCH - 1);

    gs[t] = Gsum[cls * 256 + t];
    __syncthreads();

    const int la = (target[a] == cls) ? 1 : 0;
    const bf16x8* rp = (const bf16x8*)((const ushort*)g + ((size_t)cls * BATCH + a) * DIM);
    const float* gv = &gs[la * 128];
    float dot = 0.0f;
#pragma unroll
    for (int k = 0; k < 16; ++k) {
        bf16x8 v = rp[k];
#pragma unroll
        for (int e = 0; e < 8; ++e) {
            union { unsigned u; float f; } cv;
            cv.u = ((unsigned)(unsigned short)v[e]) << 16;
            dot += cv.f * gv[k * 8 + e];
        }
    }
    int c1  = counts[cls];
    int cnt = la ? (c1 - 1) : (BATCH - c1 - 1);
    float s2v  = (dot - 1.0f) * INV_T;
    float mlpp = s2v / (float)cnt - logf(denom[idx]);
    float part = __expf(-log_vars[cls]) * mlpp;
#pragma unroll
    for (int m = 32; m; m >>= 1) part += __shfl_xor(part, m, 64);
    if ((t & 63) == 0) wred[t >> 6] = part;
    __syncthreads();
    if (t == 0)
        atomicAdd(out, -(wred[0] + wred[1] + wred[2] + wred[3]) / (float)BATCH);
}

// ---------------------------------------------------------------------------
extern "C" void kernel_launch(void* const* d_in, const int* in_sizes, int n_in,
                              void* d_out, int out_size, void* d_ws, size_t ws_size,
                              hipStream_t stream)
{
    const float* preds    = (const float*)d_in[0];   // [10,2048,128] f32
    const int*   target   = (const int*)  d_in[1];   // [2048]
    const float* log_vars = (const float*)d_in[2];   // [10]
    float* out = (float*)d_out;

    __hip_bfloat16* gbf = (__hip_bfloat16*)d_ws;              // 10*2048*128 bf16
    float* denom = (float*)((char*)d_ws + (size_t)NUM_CLASSES * BATCH * DIM * 2);
    float* Gsum  = denom + 40960;            // after the zero-filled region
    int*   counts = (int*)(Gsum + NUM_CLASSES * 256);

    normalize_kernel<<<NUM_CLASSES * BATCH / 4, 256, 0, stream>>>(preds, gbf, denom);
    gsum_kernel<<<NUM_CLASSES, 1024, 0, stream>>>(gbf, target, log_vars, Gsum, counts, out);
    gram_kernel<<<dim3(NPAIR, NUM_CLASSES), 256, 0, stream>>>(gbf, denom);
    final_kernel<<<NUM_CLASSES * BATCH / 256, 256, 0, stream>>>(
        gbf, denom, target, log_vars, Gsum, counts, out);
}

// Round 7
// 87.426 us; speedup vs baseline: 2.0748x; 1.1746x over previous
//
#include <hip/hip_runtime.h>
#include <hip/hip_bf16.h>
#include <math.h>

#define NUM_CLASSES 10
#define BATCH 2048
#define DIM 128
#define INV_T 14.285714285714286f   // 1/0.07; TEMPERATURE/BASE_TEMPERATURE = 1
#define NTILE 16                    // 2048/128 row stripes
#define NPAIR 136                   // upper-triangular 128x128 block pairs

typedef __attribute__((ext_vector_type(8))) short bf16x8;   // 8 bf16 = 4 VGPRs
typedef __attribute__((ext_vector_type(4))) float f32x4;    // MFMA accumulator

// Async 16B-per-lane global->LDS. LDS dest = wave-uniform base + lane*16.
__device__ __forceinline__ void load_lds16(const void* g, void* lds) {
    __builtin_amdgcn_global_load_lds(
        (const __attribute__((address_space(1))) unsigned int*)g,
        (__attribute__((address_space(3))) unsigned int*)lds,
        16, 0, 0);
}

// ---------------------------------------------------------------------------
// 1) Row-normalize preds -> bf16 g; fuse zeroing of denom/s2 accumulators;
//    block 0 initializes out[0] = sum(log_vars) (final_kernel atomicAdds).
// ---------------------------------------------------------------------------
__global__ __launch_bounds__(256) void normalize_kernel(
    const float* __restrict__ preds, __hip_bfloat16* __restrict__ g,
    float* __restrict__ zero_buf, const float* __restrict__ log_vars,
    float* __restrict__ out)
{
    int b = blockIdx.x;
    int t = threadIdx.x;
    if (t < 8) zero_buf[b * 8 + t] = 0.0f;   // 5120*8 = 40960 floats (denom+s2)
    if (b == 0 && t == 0) {
        float lv = 0.0f;
        for (int i = 0; i < NUM_CLASSES; ++i) lv += log_vars[i];
        out[0] = lv;
    }

    int row  = b * 4 + (t >> 6);
    int lane = t & 63;
    const float2* src = (const float2*)(preds + (size_t)row * DIM);
    float2 v = src[lane];
    float ss = v.x * v.x + v.y * v.y;
#pragma unroll
    for (int m = 32; m; m >>= 1) ss += __shfl_xor(ss, m, 64);
    float rn = 1.0f / sqrtf(ss);
    __hip_bfloat162 o;
    o.x = __float2bfloat16(v.x * rn);
    o.y = __float2bfloat16(v.y * rn);
    *(__hip_bfloat162*)(g + (size_t)row * DIM + lane * 2) = o;
}

// ---------------------------------------------------------------------------
// 2) MFMA Gram, upper-tri blocks only (round-4 verified). Async
//    global_load_lds staging, XOR-swizzled layout, merged den+sp epilogue.
// ---------------------------------------------------------------------------
__global__ __launch_bounds__(256) void gram_kernel(
    const __hip_bfloat16* __restrict__ g, const int* __restrict__ target,
    float* __restrict__ denom, float* __restrict__ s2)
{
    // decode upper-tri pair (by <= bx)
    int p = blockIdx.x;
    int by = 0, rem = NTILE;
    while (p >= rem) { p -= rem; --rem; ++by; }
    const int bx   = by + p;
    const int cls  = blockIdx.y;
    const int row0 = by * 128;
    const int col0 = bx * 128;
    const bool isDiag = (by == bx);
    const ushort* gc = (const ushort*)g + (size_t)cls * BATCH * DIM;

    __shared__ __align__(16) ushort smem[2 * 128 * 128];   // 64 KiB
    ushort* As = smem;
    ushort* Bs = smem + 128 * 128;

    const int t    = threadIdx.x;
    const int wid  = t >> 6;
    const int lane = t & 63;
    const int tx   = lane & 15;         // C/D: col = lane&15; frag row sel
    const int quad = lane >> 4;         // C/D: row = quad*4 + reg
    const int wm   = (wid >> 1) * 64;
    const int wn   = (wid & 1) * 64;

    // ---- async staging: 8 (+8) global_load_lds_dwordx4 per thread ----
    const int lr = lane >> 4;           // row-within-4
    const int lp = lane & 15;           // chunk position 0..15
#pragma unroll
    for (int s = 0; s < 8; ++s) {
        int rb = s * 16 + wid * 4;      // wave-uniform row base
        int r  = rb + lr;
        int c  = lp ^ (r & 15);         // fetch chunk c into position lp
        load_lds16(gc + (size_t)(row0 + r) * DIM + c * 8, &As[rb * 128]);
        if (!isDiag)
            load_lds16(gc + (size_t)(col0 + r) * DIM + c * 8, &Bs[rb * 128]);
    }
    __syncthreads();   // drains vmcnt before LDS reads

    // ---- MFMA main loop: K=128 in 4 slices of 32 ----
    const ushort* BsR = isDiag ? As : Bs;
    f32x4 acc[4][4] = {};
#pragma unroll
    for (int ks = 0; ks < 4; ++ks) {
        bf16x8 af[4], bg[4];
#pragma unroll
        for (int i = 0; i < 4; ++i) {
            int pa = ((ks * 4 + quad) ^ tx) * 8;   // swizzled chunk offset
            af[i] = *(const bf16x8*)&As [(wm + i * 16 + tx) * 128 + pa];
            bg[i] = *(const bf16x8*)&BsR[(wn + i * 16 + tx) * 128 + pa];
        }
#pragma unroll
        for (int i = 0; i < 4; ++i)
#pragma unroll
            for (int j = 0; j < 4; ++j)
                acc[i][j] = __builtin_amdgcn_mfma_f32_16x16x32_bf16(
                    af[i], bg[j], acc[i][j], 0, 0, 0);
    }
    __syncthreads();   // all tile reads done; safe to reuse LDS

    // ---- epilogue: register partials -> LDS transpose -> atomics ----
    unsigned laMask = 0;
#pragma unroll
    for (int i = 0; i < 4; ++i)
#pragma unroll
        for (int r = 0; r < 4; ++r)
            if (target[row0 + wm + i * 16 + quad * 4 + r] == cls)
                laMask |= 1u << (i * 4 + r);
    int lb[4];
#pragma unroll
    for (int j = 0; j < 4; ++j) lb[j] = (target[col0 + wn + j * 16 + tx] == cls);

    float2* rbuf = (float2*)smem;                    // [wid][64 x17][tx] 34816 B
    float2* cbuf = (float2*)(smem + 17408);          // [wid][64 x5][quad] 10240 B
    float2 pcol[4] = {};

#pragma unroll
    for (int i = 0; i < 4; ++i) {
        float2 prow[4] = {};
#pragma unroll
        for (int j = 0; j < 4; ++j) {
            int cg = col0 + wn + j * 16 + tx;
            int lbj = lb[j];
#pragma unroll
            for (int r = 0; r < 4; ++r) {
                int rg = row0 + wm + i * 16 + quad * 4 + r;
                float logit = acc[i][j][r] * INV_T;
                float e = __expf(logit);
                bool dg = isDiag && (cg == rg);
                e = dg ? 0.0f : e;
                bool same = (((laMask >> (i * 4 + r)) & 1) == (unsigned)lbj) && !dg;
                float sl = same ? logit : 0.0f;
                prow[r].x += e; prow[r].y += sl;
                pcol[j].x += e; pcol[j].y += sl;
            }
        }
#pragma unroll
        for (int r = 0; r < 4; ++r)
            rbuf[wid * 1088 + (i * 16 + quad * 4 + r) * 17 + tx] = prow[r];
    }
#pragma unroll
    for (int j = 0; j < 4; ++j)
        cbuf[wid * 320 + (j * 16 + tx) * 5 + quad] = pcol[j];
    __syncthreads();

    if (t < 128) {
        // rows: wids 2*grp, 2*grp+1 share wm = 64*grp
        int rl = t & 63, grp = t >> 6;
        float den = 0.0f, sp = 0.0f;
#pragma unroll
        for (int w = 0; w < 2; ++w) {
            int base = (2 * grp + w) * 1088 + rl * 17;
#pragma unroll
            for (int x = 0; x < 16; ++x) {
                float2 v = rbuf[base + x];
                den += v.x; sp += v.y;
            }
        }
        atomicAdd(&denom[cls * BATCH + row0 + t], den);
        atomicAdd(&s2   [cls * BATCH + row0 + t], sp);
    } else if (!isDiag) {
        // cols: wids grp, grp+2 share wn = 64*grp
        int u = t - 128;
        int cl = u & 63, grp = u >> 6;
        float den = 0.0f, sp = 0.0f;
#pragma unroll
        for (int w = 0; w < 2; ++w) {
            int base = (grp + 2 * w) * 320 + cl * 5;
#pragma unroll
            for (int q = 0; q < 4; ++q) {
                float2 v = cbuf[base + q];
                den += v.x; sp += v.y;
            }
        }
        atomicAdd(&denom[cls * BATCH + col0 + u], den);
        atomicAdd(&s2   [cls * BATCH + col0 + u], sp);
    }
}

// ---------------------------------------------------------------------------
// 3) Finalize, parallel: 80 blocks x 256 threads, one thread per (cls,row).
//    Each block is class-uniform; recomputes its class count from target
//    (2048 cached reads). Accumulates into out via device atomicAdd.
// ---------------------------------------------------------------------------
__global__ __launch_bounds__(256) void final_kernel(
    const float* __restrict__ denom, const float* __restrict__ s2,
    const int* __restrict__ target, const float* __restrict__ log_vars,
    float* __restrict__ out)
{
    __shared__ int cw[4];
    __shared__ float wred[4];
    const int t   = threadIdx.x;
    const int idx = blockIdx.x * 256 + t;
    const int cls = idx >> 11;            // block-uniform (2048 % 256 == 0)
    const int a   = idx & (BATCH - 1);

    // block-wide count of (target == cls)
    int c = 0;
#pragma unroll
    for (int k = 0; k < 8; ++k) c += (target[t * 8 + k] == cls);
#pragma unroll
    for (int m = 1; m < 64; m <<= 1) c += __shfl_xor(c, m, 64);
    if ((t & 63) == 0) cw[t >> 6] = c;
    __syncthreads();
    const int c1 = cw[0] + cw[1] + cw[2] + cw[3];

    const int la  = (target[a] == cls);
    const int cnt = la ? (c1 - 1) : (BATCH - c1 - 1);
    float mlpp = s2[idx] / (float)cnt - logf(denom[idx]);
    float part = __expf(-log_vars[cls]) * mlpp;
#pragma unroll
    for (int m = 32; m; m >>= 1) part += __shfl_xor(part, m, 64);
    if ((t & 63) == 0) wred[t >> 6] = part;
    __syncthreads();
    if (t == 0)
        atomicAdd(out, -(wred[0] + wred[1] + wred[2] + wred[3]) / (float)BATCH);
}

// ---------------------------------------------------------------------------
extern "C" void kernel_launch(void* const* d_in, const int* in_sizes, int n_in,
                              void* d_out, int out_size, void* d_ws, size_t ws_size,
                              hipStream_t stream)
{
    const float* preds    = (const float*)d_in[0];   // [10,2048,128] f32
    const int*   target   = (const int*)  d_in[1];   // [2048]
    const float* log_vars = (const float*)d_in[2];   // [10]
    float* out = (float*)d_out;

    __hip_bfloat16* gbf = (__hip_bfloat16*)d_ws;              // 10*2048*128 bf16
    float* denom = (float*)((char*)d_ws + (size_t)NUM_CLASSES * BATCH * DIM * 2);
    float* s2    = denom + (size_t)NUM_CLASSES * BATCH;

    normalize_kernel<<<NUM_CLASSES * BATCH / 4, 256, 0, stream>>>(
        preds, gbf, denom, log_vars, out);
    gram_kernel<<<dim3(NPAIR, NUM_CLASSES), 256, 0, stream>>>(gbf, target, denom, s2);
    final_kernel<<<NUM_CLASSES * BATCH / 256, 256, 0, stream>>>(
        denom, s2, target, log_vars, out);
}